// Round 4
// baseline (248.176 us; speedup 1.0000x reference)
//
#include <hip/hip_runtime.h>
#include <hip/hip_bf16.h>

namespace {

constexpr int kB = 512, kT = 512, kN = 128, kM = 64, kU = 64;
constexpr int TT = 64;   // t-tile staged in LDS

// tanh(x) = 1 - 2/(exp(2x)+1): monotone-safe at +/-inf, no NaN.
__device__ __forceinline__ float fast_tanh(float x) {
  return 1.0f - 2.0f / (__expf(2.0f * x) + 1.0f);
}

struct Smem {
  float xs[TT][kN];        // 32 KB
  float w1s[TT][kU];       // 16 KB
  float qp[kU];
  float sred[16][kN + 1];  // +1 pad
  float sn[kN];
  float aw[kN];
};

// One block per batch b. 256 threads. All f32 in / f32 out.
// Phase 0: q_proj[u] (+biases) -> LDS
// Phase 1: pre[n][u] = sum_t x[b,t,n]*w1[t,u], t-tiled, 8n x 4u regs/thread
// Phase 2: tanh, *v, reduce over u -> s[n]; softmax over n -> aw (LDS)
// Phase 3: ctx[b,t] = sum_n aw[n]*x[b,t,n], quad-per-row
__global__ __launch_bounds__(256) void fused_kernel(
    const float* __restrict__ x,    // (B,T,N)
    const float* __restrict__ hs,   // (B,M)
    const float* __restrict__ cs,   // (B,M)
    const float* __restrict__ w1,   // (T,U)
    const float* __restrict__ w1b,  // (U)
    const float* __restrict__ w2,   // (2M,U)
    const float* __restrict__ w2b,  // (U)
    const float* __restrict__ vk,   // (U,1)
    const float* __restrict__ vb,   // (1)
    float* __restrict__ ctx_out,    // (B,T) f32
    float* __restrict__ aw_out)     // (B,1,N) f32
{
  __shared__ Smem s;
  const int b = blockIdx.x;
  const int tid = threadIdx.x;

  // ---- Phase 0 (threads 0..63): q_proj + w2_bias + w1_bias ----
  if (tid < kU) {
    float a0 = w2b[tid] + w1b[tid];
    for (int k = 0; k < kM; ++k)
      a0 = fmaf(hs[(size_t)b * kM + k], w2[k * kU + tid], a0);
    for (int k = 0; k < kM; ++k)
      a0 = fmaf(cs[(size_t)b * kM + k], w2[(kM + k) * kU + tid], a0);
    s.qp[tid] = a0;
  }

  // Register tile: 8 n x 4 u per thread.
  const int n0 = (tid >> 4) * 8;
  const int u0 = (tid & 15) * 4;

  float acc[8][4];
#pragma unroll
  for (int j = 0; j < 8; ++j)
#pragma unroll
    for (int i = 0; i < 4; ++i) acc[j][i] = 0.f;

  // ---- Phase 1 ----
  for (int t0 = 0; t0 < kT; t0 += TT) {
    __syncthreads();
    {
      const float4* xp = (const float4*)(x + ((size_t)b * kT + t0) * kN);
#pragma unroll
      for (int i = 0; i < 8; ++i) {
        int idx = tid + i * 256;                       // 2048 float4 = 64x128
        *(float4*)&s.xs[idx >> 5][(idx & 31) * 4] = xp[idx];
      }
      const float4* wp = (const float4*)(w1 + (size_t)t0 * kU);
#pragma unroll
      for (int i = 0; i < 4; ++i) {
        int idx = tid + i * 256;                       // 1024 float4 = 64x64
        *(float4*)&s.w1s[idx >> 4][(idx & 15) * 4] = wp[idx];
      }
    }
    __syncthreads();

#pragma unroll 4
    for (int tt = 0; tt < TT; ++tt) {
      float xv[8], wv[4];
      *(float4*)&xv[0] = *(const float4*)&s.xs[tt][n0];
      *(float4*)&xv[4] = *(const float4*)&s.xs[tt][n0 + 4];
      *(float4*)&wv[0] = *(const float4*)&s.w1s[tt][u0];
#pragma unroll
      for (int j = 0; j < 8; ++j)
#pragma unroll
        for (int i = 0; i < 4; ++i)
          acc[j][i] = fmaf(xv[j], wv[i], acc[j][i]);
    }
  }

  // ---- Phase 2: tanh + *v, reduce over u; softmax over n ----
  float qv[4], vv[4];
#pragma unroll
  for (int i = 0; i < 4; ++i) {
    qv[i] = s.qp[u0 + i];
    vv[i] = vk[u0 + i];
  }
#pragma unroll
  for (int j = 0; j < 8; ++j) {
    float p = 0.f;
#pragma unroll
    for (int i = 0; i < 4; ++i)
      p = fmaf(fast_tanh(acc[j][i] + qv[i]), vv[i], p);
    s.sred[tid & 15][n0 + j] = p;
  }
  __syncthreads();
  if (tid < kN) {
    float v = vb[0];
#pragma unroll
    for (int g = 0; g < 16; ++g) v += s.sred[g][tid];
    s.sn[tid] = v;
  }
  __syncthreads();

  if (tid < 64) {   // wave 0: softmax over 128 (2 per lane)
    float s0 = s.sn[tid], s1 = s.sn[tid + 64];
    float m = fmaxf(s0, s1);
#pragma unroll
    for (int off = 32; off > 0; off >>= 1) m = fmaxf(m, __shfl_xor(m, off));
    float e0 = __expf(s0 - m), e1 = __expf(s1 - m);
    float se = e0 + e1;
#pragma unroll
    for (int off = 32; off > 0; off >>= 1) se += __shfl_xor(se, off);
    float inv = 1.0f / se;
    float a0 = e0 * inv, a1 = e1 * inv;
    s.aw[tid] = a0;
    s.aw[tid + 64] = a1;
    aw_out[(size_t)b * kN + tid] = a0;
    aw_out[(size_t)b * kN + tid + 64] = a1;
  }
  __syncthreads();

  // ---- Phase 3: ctx[b,t] = sum_n aw[n] * x[b,t,n]; quad per row ----
  const int lr = tid & 3;
  const int qrow = tid >> 2;   // 0..63
  for (int rg = 0; rg < 8; ++rg) {
    const int r = rg * 64 + qrow;
    const float4* xp = (const float4*)(x + ((size_t)b * kT + r) * kN);
    float a = 0.f;
#pragma unroll
    for (int k = 0; k < 8; ++k) {
      int i = lr + k * 4;        // 32 float4 per row, quad-covered
      float4 v = xp[i];
      const float* w = &s.aw[i * 4];
      a = fmaf(v.x, w[0], a);
      a = fmaf(v.y, w[1], a);
      a = fmaf(v.z, w[2], a);
      a = fmaf(v.w, w[3], a);
    }
    a += __shfl_xor(a, 1);
    a += __shfl_xor(a, 2);
    if (lr == 0) ctx_out[(size_t)b * kT + r] = a;
  }
}

}  // namespace

extern "C" void kernel_launch(void* const* d_in, const int* in_sizes, int n_in,
                              void* d_out, int out_size, void* d_ws, size_t ws_size,
                              hipStream_t stream) {
  const float* x   = (const float*)d_in[0];
  const float* hs  = (const float*)d_in[1];
  const float* cs  = (const float*)d_in[2];
  const float* w1  = (const float*)d_in[3];
  const float* w1b = (const float*)d_in[4];
  const float* w2  = (const float*)d_in[5];
  const float* w2b = (const float*)d_in[6];
  const float* vk  = (const float*)d_in[7];
  const float* vb  = (const float*)d_in[8];

  float* out = (float*)d_out;
  float* ctx = out;                      // context_vector (B,T) f32
  float* awo = out + (size_t)kB * kT;    // attention_weights (B,1,N) f32

  hipLaunchKernelGGL(fused_kernel, dim3(kB), dim3(256), 0, stream,
                     x, hs, cs, w1, w1b, w2, w2b, vk, vb, ctx, awo);
}

// Round 5
// 226.783 us; speedup vs baseline: 1.0943x; 1.0943x over previous
//
#include <hip/hip_runtime.h>
#include <hip/hip_bf16.h>

namespace {

constexpr int kB = 512, kT = 512, kN = 128, kM = 64, kU = 64;
constexpr int TT = 64;          // t-tile per staging round
constexpr int SX = 68;          // padded row stride (u32): 16B-aligned + bank-balanced

typedef __attribute__((ext_vector_type(8))) short short8;   // bf16x8 MFMA frag
typedef __attribute__((ext_vector_type(4))) float f32x4;    // MFMA acc

// f32 -> (bf16 hi | bf16 lo) packed in one u32. hi = rne(v); lo = rne(v - hi).
__device__ __forceinline__ unsigned pack_hl(float v) {
  unsigned u = __float_as_uint(v);
  unsigned hs = (u + 0x7fffu + ((u >> 16) & 1u)) >> 16;
  float lo = v - __uint_as_float(hs << 16);
  unsigned ul = __float_as_uint(lo);
  unsigned ls = (ul + 0x7fffu + ((ul >> 16) & 1u)) >> 16;
  return (hs << 16) | (ls & 0xffffu);
}

__device__ __forceinline__ float fast_tanh(float x) {
  return 1.0f - 2.0f / (__expf(2.0f * x) + 1.0f);
}

union FragU { unsigned u[4]; short8 s; };

// 8 packed u32 -> hi-frag (8 bf16) + lo-frag (8 bf16), element order preserved.
__device__ __forceinline__ void unpack_hl(const unsigned* p, short8& hi, short8& lo) {
  FragU H, L;
#pragma unroll
  for (int j = 0; j < 4; ++j) {
    unsigned a = p[2 * j], b = p[2 * j + 1];
    H.u[j] = (a >> 16) | (b & 0xffff0000u);
    L.u[j] = (a & 0xffffu) | (b << 16);
  }
  hi = H.s; lo = L.s;
}

struct Smem {
  unsigned xsT[kN * SX];   // x-tile transposed: [n][t], packed hi|lo  (34816 B)
  unsigned w1T[kU * SX];   // w1-tile transposed: [u][t], packed hi|lo (17408 B)
  float qp[kU];
  float sn[kN];
  float aw[kN];
};

// One block per batch b. 512 threads = 8 waves.
// Phase 0: q_proj[u] (+biases) -> LDS
// Phase 1: pre[n][u] = sum_t x[t,n]*w1[t,u] via split-bf16 MFMA 16x16x32.
//          Wave w owns m-tile n in [16w,16w+16), all 4 u-tiles.
// Phase 2: tanh, *v, lane-group reduce -> sn[n]; softmax -> aw (LDS + out)
// Phase 3: ctx[t] = sum_n aw[n]*x[t,n], quad-per-row from global (L3-hot)
__global__ __launch_bounds__(512, 4) void fused_kernel(
    const float* __restrict__ x,    // (B,T,N)
    const float* __restrict__ hs,   // (B,M)
    const float* __restrict__ cs,   // (B,M)
    const float* __restrict__ w1,   // (T,U)
    const float* __restrict__ w1b,  // (U)
    const float* __restrict__ w2,   // (2M,U)
    const float* __restrict__ w2b,  // (U)
    const float* __restrict__ vk,   // (U,1)
    const float* __restrict__ vb,   // (1) — softmax-invariant, unused
    float* __restrict__ ctx_out,    // (B,T)
    float* __restrict__ aw_out)     // (B,1,N)
{
  __shared__ Smem s;
  const int b = blockIdx.x;
  const int tid = threadIdx.x;

  // ---- Phase 0 (threads 0..63): q_proj + w2_bias + w1_bias ----
  if (tid < kU) {
    float a0 = w2b[tid] + w1b[tid];
    for (int k = 0; k < kM; ++k)
      a0 = fmaf(hs[(size_t)b * kM + k], w2[k * kU + tid], a0);
    for (int k = 0; k < kM; ++k)
      a0 = fmaf(cs[(size_t)b * kM + k], w2[(kM + k) * kU + tid], a0);
    s.qp[tid] = a0;
  }

  const int lane = tid & 63;
  const int w8 = tid >> 6;        // wave id 0..7 -> m-tile base 16*w8
  const int c = lane & 15;        // MFMA col / frag row selector
  const int q = lane >> 4;        // MFMA quad

  f32x4 acc[4];
#pragma unroll
  for (int ut = 0; ut < 4; ++ut) acc[ut] = (f32x4){0.f, 0.f, 0.f, 0.f};

  // staging identities
  const int n2 = tid & 63;        // x: handles rows n=2*n2, 2*n2+1
  const int halfx = tid >> 6;     // x: quad-group
  const int u2 = tid & 31;        // w1: rows u=2*u2, 2*u2+1
  const int grpw = tid >> 5;      // w1: quad index 0..15

  // ---- Phase 1 ----
  for (int t0 = 0; t0 < kT; t0 += TT) {
    __syncthreads();
    // x-tile: gather 4 consecutive t per (thread,row-pair) from coalesced row
    // loads, pack f32 -> hi|lo u32, write transposed as one b128 per row.
#pragma unroll
    for (int qi = 0; qi < 2; ++qi) {
      const int tq = halfx + 8 * qi;           // t-quad 0..15
      unsigned p0[4], p1[4];
#pragma unroll
      for (int j = 0; j < 4; ++j) {
        float2 v = *(const float2*)&x[((size_t)b * kT + t0 + 4 * tq + j) * kN + 2 * n2];
        p0[j] = pack_hl(v.x);
        p1[j] = pack_hl(v.y);
      }
      *(uint4*)&s.xsT[(2 * n2) * SX + 4 * tq]     = make_uint4(p0[0], p0[1], p0[2], p0[3]);
      *(uint4*)&s.xsT[(2 * n2 + 1) * SX + 4 * tq] = make_uint4(p1[0], p1[1], p1[2], p1[3]);
    }
    // w1-tile: same pattern, one t-quad per thread-group.
    {
      const int tq = grpw;
      unsigned p0[4], p1[4];
#pragma unroll
      for (int j = 0; j < 4; ++j) {
        float2 v = *(const float2*)&w1[(size_t)(t0 + 4 * tq + j) * kU + 2 * u2];
        p0[j] = pack_hl(v.x);
        p1[j] = pack_hl(v.y);
      }
      *(uint4*)&s.w1T[(2 * u2) * SX + 4 * tq]     = make_uint4(p0[0], p0[1], p0[2], p0[3]);
      *(uint4*)&s.w1T[(2 * u2 + 1) * SX + 4 * tq] = make_uint4(p1[0], p1[1], p1[2], p1[3]);
    }
    __syncthreads();

    // K-loop: 2 steps of k=32. A-frag: row n=16*w8+c, cols kk+8q..+8.
#pragma unroll
    for (int kk = 0; kk < TT; kk += 32) {
      short8 ahi, alo;
      {
        unsigned raw[8];
        const unsigned* pa = &s.xsT[(16 * w8 + c) * SX + kk + 8 * q];
        *(uint4*)&raw[0] = *(const uint4*)pa;
        *(uint4*)&raw[4] = *(const uint4*)(pa + 4);
        unpack_hl(raw, ahi, alo);
      }
#pragma unroll
      for (int ut = 0; ut < 4; ++ut) {
        unsigned raw[8];
        const unsigned* pb = &s.w1T[(16 * ut + c) * SX + kk + 8 * q];
        *(uint4*)&raw[0] = *(const uint4*)pb;
        *(uint4*)&raw[4] = *(const uint4*)(pb + 4);
        short8 bhi, blo;
        unpack_hl(raw, bhi, blo);
        acc[ut] = __builtin_amdgcn_mfma_f32_16x16x32_bf16(ahi, bhi, acc[ut], 0, 0, 0);
        acc[ut] = __builtin_amdgcn_mfma_f32_16x16x32_bf16(ahi, blo, acc[ut], 0, 0, 0);
        acc[ut] = __builtin_amdgcn_mfma_f32_16x16x32_bf16(alo, bhi, acc[ut], 0, 0, 0);
      }
    }
  }

  // ---- Phase 2: tanh + *v, reduce over u (16 lanes), scores -> softmax ----
  // Lane holds pre[n][u] for u = 16*ut + c, n = 16*w8 + 4*q + r.
  float qv[4], vv[4];
#pragma unroll
  for (int ut = 0; ut < 4; ++ut) {
    qv[ut] = s.qp[16 * ut + c];
    vv[ut] = vk[16 * ut + c];
  }
  float pr[4];
#pragma unroll
  for (int r = 0; r < 4; ++r) {
    float p = 0.f;
#pragma unroll
    for (int ut = 0; ut < 4; ++ut)
      p = fmaf(fast_tanh(acc[ut][r] + qv[ut]), vv[ut], p);
    p += __shfl_xor(p, 1);
    p += __shfl_xor(p, 2);
    p += __shfl_xor(p, 4);
    p += __shfl_xor(p, 8);
    pr[r] = p;
  }
  if (c == 0) {
#pragma unroll
    for (int r = 0; r < 4; ++r) s.sn[16 * w8 + 4 * q + r] = pr[r];
  }
  __syncthreads();

  if (tid < 64) {   // wave 0: softmax over 128 (v_bias shift cancels)
    float s0 = s.sn[tid], s1 = s.sn[tid + 64];
    float m = fmaxf(s0, s1);
#pragma unroll
    for (int off = 32; off > 0; off >>= 1) m = fmaxf(m, __shfl_xor(m, off));
    float e0 = __expf(s0 - m), e1 = __expf(s1 - m);
    float se = e0 + e1;
#pragma unroll
    for (int off = 32; off > 0; off >>= 1) se += __shfl_xor(se, off);
    float inv = 1.0f / se;
    float a0 = e0 * inv, a1 = e1 * inv;
    s.aw[tid] = a0;
    s.aw[tid + 64] = a1;
    aw_out[(size_t)b * kN + tid] = a0;
    aw_out[(size_t)b * kN + tid + 64] = a1;
  }
  __syncthreads();

  // ---- Phase 3: ctx[t] = sum_n aw[n]*x[t,n]; quad per row, 4 passes ----
  const int lr = tid & 3;
  const int rr = tid >> 2;   // 0..127
#pragma unroll
  for (int rg = 0; rg < 4; ++rg) {
    const int r = rg * 128 + rr;
    const float4* xp = (const float4*)(x + ((size_t)b * kT + r) * kN);
    float a = 0.f;
#pragma unroll
    for (int k = 0; k < 8; ++k) {
      int i = lr + k * 4;
      float4 v = xp[i];
      const float* wa = &s.aw[i * 4];
      a = fmaf(v.x, wa[0], a);
      a = fmaf(v.y, wa[1], a);
      a = fmaf(v.z, wa[2], a);
      a = fmaf(v.w, wa[3], a);
    }
    a += __shfl_xor(a, 1);
    a += __shfl_xor(a, 2);
    if (lr == 0) ctx_out[(size_t)b * kT + r] = a;
  }
  (void)vb;
}

}  // namespace

extern "C" void kernel_launch(void* const* d_in, const int* in_sizes, int n_in,
                              void* d_out, int out_size, void* d_ws, size_t ws_size,
                              hipStream_t stream) {
  const float* x   = (const float*)d_in[0];
  const float* hs  = (const float*)d_in[1];
  const float* cs  = (const float*)d_in[2];
  const float* w1  = (const float*)d_in[3];
  const float* w1b = (const float*)d_in[4];
  const float* w2  = (const float*)d_in[5];
  const float* w2b = (const float*)d_in[6];
  const float* vk  = (const float*)d_in[7];
  const float* vb  = (const float*)d_in[8];

  float* out = (float*)d_out;
  float* ctx = out;                      // context_vector (B,T)
  float* awo = out + (size_t)kB * kT;    // attention_weights (B,1,N)

  hipLaunchKernelGGL(fused_kernel, dim3(kB), dim3(512), 0, stream,
                     x, hs, cs, w1, w1b, w2, w2b, vk, vb, ctx, awo);
}